// Round 1
// baseline (1285.085 us; speedup 1.0000x reference)
//
#include <hip/hip_runtime.h>
#include <hip/hip_bf16.h>

// GCNConv: out = D * (A @ (D * (X@W))) + bias,  D = rsqrt(rowsum(A)+1)
// N=100000 nodes, E=640000 edges, C=128 channels (in==out).
// Phases: deg scatter -> fused GEMM+D scale -> edge gather/scatter (atomics) -> finalize.

#define N_CH 128

// ---- Phase 1: deg[r] += vals[e] ------------------------------------------
__global__ __launch_bounds__(256) void deg_kernel(const int* __restrict__ row,
                                                  const float* __restrict__ vals,
                                                  float* __restrict__ deg, int E) {
    int e = blockIdx.x * 256 + threadIdx.x;
    if (e < E) atomicAdd(&deg[row[e]], vals[e]);
}

// ---- Phase 2: Y[n,:] = rsqrt(deg[n]+1) * (X[n,:] @ W) --------------------
// Block: 256 threads, 32 rows x 128 cols tile. W (64KB) + X tile (16KB) in LDS.
// Thread (t): cols 4*(t&31), rows 4*(t>>5). acc[4][4]. k unrolled by 4 (b128 LDS reads).
__global__ __launch_bounds__(256) void gemm_kernel(const float* __restrict__ X,
                                                   const float* __restrict__ W,
                                                   const float* __restrict__ deg,
                                                   float* __restrict__ Y, int N) {
    __shared__ float Ws[N_CH * N_CH];   // 64 KB
    __shared__ float Xs[32 * N_CH];     // 16 KB
    const int t = threadIdx.x;
    const int row0 = blockIdx.x * 32;   // N divisible by 32 (100000 = 32*3125)

    // stage W: 4096 float4, 16 per thread (coalesced)
    const float4* W4 = (const float4*)W;
    float4* Ws4 = (float4*)Ws;
#pragma unroll
    for (int j = 0; j < 16; ++j) Ws4[t + 256 * j] = W4[t + 256 * j];
    // stage X tile: 1024 float4, 4 per thread
    const float4* X4 = (const float4*)(X + (size_t)row0 * N_CH);
    float4* Xs4 = (float4*)Xs;
#pragma unroll
    for (int j = 0; j < 4; ++j) Xs4[t + 256 * j] = X4[t + 256 * j];
    __syncthreads();

    const int cg = (t & 31) * 4;   // col base (float4)
    const int rg = (t >> 5) * 4;   // row base (4 rows)
    float acc[4][4] = {};

#pragma unroll 4
    for (int k = 0; k < N_CH; k += 4) {
        float4 w0 = *(const float4*)(Ws + (k + 0) * N_CH + cg);
        float4 w1 = *(const float4*)(Ws + (k + 1) * N_CH + cg);
        float4 w2 = *(const float4*)(Ws + (k + 2) * N_CH + cg);
        float4 w3 = *(const float4*)(Ws + (k + 3) * N_CH + cg);
#pragma unroll
        for (int i = 0; i < 4; ++i) {
            float4 x = *(const float4*)(Xs + (rg + i) * N_CH + k);
            acc[i][0] += x.x * w0.x + x.y * w1.x + x.z * w2.x + x.w * w3.x;
            acc[i][1] += x.x * w0.y + x.y * w1.y + x.z * w2.y + x.w * w3.y;
            acc[i][2] += x.x * w0.z + x.y * w1.z + x.z * w2.z + x.w * w3.z;
            acc[i][3] += x.x * w0.w + x.y * w1.w + x.z * w2.w + x.w * w3.w;
        }
    }

#pragma unroll
    for (int i = 0; i < 4; ++i) {
        int r = row0 + rg + i;
        float d = rsqrtf(deg[r] + 1.0f);
        float4 o;
        o.x = acc[i][0] * d; o.y = acc[i][1] * d;
        o.z = acc[i][2] * d; o.w = acc[i][3] * d;
        *(float4*)(Y + (size_t)r * N_CH + cg) = o;
    }
}

// ---- Phase 3: out[row[e],:] += vals[e] * Y[col[e],:] ---------------------
// One thread per (edge, 4 channels): 32 threads/edge, float4 gather + 4 atomics.
__global__ __launch_bounds__(256) void scatter_kernel(const int* __restrict__ row,
                                                      const int* __restrict__ col,
                                                      const float* __restrict__ vals,
                                                      const float* __restrict__ Y,
                                                      float* __restrict__ out, int E) {
    unsigned gid = blockIdx.x * 256u + threadIdx.x;
    int e = gid >> 5;
    if (e >= E) return;
    int c = (gid & 31) * 4;
    int r = row[e];
    int cl = col[e];
    float v = vals[e];
    float4 y = *(const float4*)(Y + (size_t)cl * N_CH + c);
    float* o = out + (size_t)r * N_CH + c;
    atomicAdd(o + 0, v * y.x);
    atomicAdd(o + 1, v * y.y);
    atomicAdd(o + 2, v * y.z);
    atomicAdd(o + 3, v * y.w);
}

// ---- Phase 4: out = D * out + bias ---------------------------------------
__global__ __launch_bounds__(256) void finalize_kernel(float* __restrict__ out,
                                                       const float* __restrict__ deg,
                                                       const float* __restrict__ bias,
                                                       int N) {
    unsigned gid = blockIdx.x * 256u + threadIdx.x;  // float4 index
    int n = gid >> 5;
    if (n >= N) return;
    int c = (gid & 31) * 4;
    float d = rsqrtf(deg[n] + 1.0f);
    float4 b = *(const float4*)(bias + c);
    float4* p = (float4*)(out + (size_t)n * N_CH + c);
    float4 o = *p;
    o.x = o.x * d + b.x;
    o.y = o.y * d + b.y;
    o.z = o.z * d + b.z;
    o.w = o.w * d + b.w;
    *p = o;
}

extern "C" void kernel_launch(void* const* d_in, const int* in_sizes, int n_in,
                              void* d_out, int out_size, void* d_ws, size_t ws_size,
                              hipStream_t stream) {
    const int*   row  = (const int*)d_in[0];
    const int*   col  = (const int*)d_in[1];
    const float* vals = (const float*)d_in[2];
    const float* X    = (const float*)d_in[3];
    const float* W    = (const float*)d_in[4];
    const float* bias = (const float*)d_in[5];
    float* out = (float*)d_out;

    const int E = in_sizes[0];
    const int N = in_sizes[3] / N_CH;

    // workspace layout: Y [N*128] then deg [N]
    float* Y   = (float*)d_ws;
    float* deg = Y + (size_t)N * N_CH;

    hipMemsetAsync(deg, 0, (size_t)N * sizeof(float), stream);
    hipMemsetAsync(out, 0, (size_t)N * N_CH * sizeof(float), stream);

    deg_kernel<<<(E + 255) / 256, 256, 0, stream>>>(row, vals, deg, E);
    gemm_kernel<<<(N + 31) / 32, 256, 0, stream>>>(X, W, deg, Y, N);

    unsigned scatter_threads = (unsigned)E * 32u;
    scatter_kernel<<<(scatter_threads + 255) / 256, 256, 0, stream>>>(row, col, vals, Y, out, E);

    unsigned fin_threads = (unsigned)N * 32u;
    finalize_kernel<<<(fin_threads + 255) / 256, 256, 0, stream>>>(out, deg, bias, N);
}

// Round 2
// 316.965 us; speedup vs baseline: 4.0543x; 4.0543x over previous
//
#include <hip/hip_runtime.h>
#include <hip/hip_bf16.h>

// GCNConv: out = D * (A @ (D * (X@W))) + bias,  D = rsqrt(rowsum(A)+1)
// N=100000 nodes, E=640000 edges, C=128.
// Pipeline: deg+count -> scan -> CSR build -> fused GEMM+Dscale -> gather(+finalize).
// Round 2: replaced 82M-f32-atomic scatter (1074us, VALUBusy 0.9%) with
// CSR build + register-accumulating gather, fusing the D*x+bias epilogue.

#define N_CH 128

// ---- deg[r] += vals[e]; cnt[r] += 1 --------------------------------------
__global__ __launch_bounds__(256) void degcnt_kernel(const int* __restrict__ row,
                                                     const float* __restrict__ vals,
                                                     float* __restrict__ deg,
                                                     int* __restrict__ cnt, int E) {
    int e = blockIdx.x * 256 + threadIdx.x;
    if (e < E) {
        int r = row[e];
        atomicAdd(&deg[r], vals[e]);
        atomicAdd(&cnt[r], 1);
    }
}

// ---- exclusive scan of cnt -> pos (3-kernel 2-level scan) ----------------
__global__ __launch_bounds__(256) void scan1_kernel(const int* __restrict__ cnt,
                                                    int* __restrict__ pos,
                                                    int* __restrict__ bsum, int N) {
    __shared__ int s[256];
    int t = threadIdx.x;
    int i = blockIdx.x * 256 + t;
    int v = (i < N) ? cnt[i] : 0;
    s[t] = v;
    __syncthreads();
    for (int off = 1; off < 256; off <<= 1) {
        int x = (t >= off) ? s[t - off] : 0;
        __syncthreads();
        s[t] += x;
        __syncthreads();
    }
    if (i < N) pos[i] = s[t] - v;           // exclusive
    if (t == 255) bsum[blockIdx.x] = s[t];  // block total
}

__global__ __launch_bounds__(512) void scan2_kernel(int* __restrict__ bsum, int nb) {
    __shared__ int s[512];
    int t = threadIdx.x;
    int v = (t < nb) ? bsum[t] : 0;
    s[t] = v;
    __syncthreads();
    for (int off = 1; off < 512; off <<= 1) {
        int x = (t >= off) ? s[t - off] : 0;
        __syncthreads();
        s[t] += x;
        __syncthreads();
    }
    if (t < nb) bsum[t] = s[t] - v;         // exclusive block offsets
}

__global__ __launch_bounds__(256) void scan3_kernel(int* __restrict__ pos,
                                                    const int* __restrict__ bsum, int N) {
    int i = blockIdx.x * 256 + threadIdx.x;
    if (i < N) pos[i] += bsum[blockIdx.x];
}

// ---- CSR build: place (col,val) into row-sorted slots --------------------
// After this kernel: pos[r] == rowptr[r+1].
__global__ __launch_bounds__(256) void csr_kernel(const int* __restrict__ row,
                                                  const int* __restrict__ col,
                                                  const float* __restrict__ vals,
                                                  int* __restrict__ pos,
                                                  int* __restrict__ ecol,
                                                  float* __restrict__ eval, int E) {
    int e = blockIdx.x * 256 + threadIdx.x;
    if (e < E) {
        int r = row[e];
        int p = atomicAdd(&pos[r], 1);
        ecol[p] = col[e];
        eval[p] = vals[e];
    }
}

// ---- Y[n,:] = rsqrt(deg[n]+1) * (X[n,:] @ W) -----------------------------
__global__ __launch_bounds__(256) void gemm_kernel(const float* __restrict__ X,
                                                   const float* __restrict__ W,
                                                   const float* __restrict__ deg,
                                                   float* __restrict__ Y, int N) {
    __shared__ float Ws[N_CH * N_CH];   // 64 KB
    __shared__ float Xs[32 * N_CH];     // 16 KB
    const int t = threadIdx.x;
    const int row0 = blockIdx.x * 32;

    const float4* W4 = (const float4*)W;
    float4* Ws4 = (float4*)Ws;
#pragma unroll
    for (int j = 0; j < 16; ++j) Ws4[t + 256 * j] = W4[t + 256 * j];
    const float4* X4 = (const float4*)(X + (size_t)row0 * N_CH);
    float4* Xs4 = (float4*)Xs;
#pragma unroll
    for (int j = 0; j < 4; ++j) Xs4[t + 256 * j] = X4[t + 256 * j];
    __syncthreads();

    const int cg = (t & 31) * 4;
    const int rg = (t >> 5) * 4;
    float acc[4][4] = {};

#pragma unroll 4
    for (int k = 0; k < N_CH; k += 4) {
        float4 w0 = *(const float4*)(Ws + (k + 0) * N_CH + cg);
        float4 w1 = *(const float4*)(Ws + (k + 1) * N_CH + cg);
        float4 w2 = *(const float4*)(Ws + (k + 2) * N_CH + cg);
        float4 w3 = *(const float4*)(Ws + (k + 3) * N_CH + cg);
#pragma unroll
        for (int i = 0; i < 4; ++i) {
            float4 x = *(const float4*)(Xs + (rg + i) * N_CH + k);
            acc[i][0] += x.x * w0.x + x.y * w1.x + x.z * w2.x + x.w * w3.x;
            acc[i][1] += x.x * w0.y + x.y * w1.y + x.z * w2.y + x.w * w3.y;
            acc[i][2] += x.x * w0.z + x.y * w1.z + x.z * w2.z + x.w * w3.z;
            acc[i][3] += x.x * w0.w + x.y * w1.w + x.z * w2.w + x.w * w3.w;
        }
    }

#pragma unroll
    for (int i = 0; i < 4; ++i) {
        int r = row0 + rg + i;
        float d = rsqrtf(deg[r] + 1.0f);
        float4 o;
        o.x = acc[i][0] * d; o.y = acc[i][1] * d;
        o.z = acc[i][2] * d; o.w = acc[i][3] * d;
        *(float4*)(Y + (size_t)r * N_CH + cg) = o;
    }
}

// ---- gather: out[n,:] = D[n] * sum_e val_e * Y[col_e,:] + bias -----------
// 32 threads (half-wave) per node, float4 per lane, register accumulate.
__global__ __launch_bounds__(256) void gather_kernel(const int* __restrict__ pos,
                                                     const int* __restrict__ ecol,
                                                     const float* __restrict__ eval,
                                                     const float* __restrict__ Y,
                                                     const float* __restrict__ deg,
                                                     const float* __restrict__ bias,
                                                     float* __restrict__ out, int N) {
    unsigned gid = blockIdx.x * 256u + threadIdx.x;
    int n = gid >> 5;
    if (n >= N) return;
    int lane = gid & 31;
    int c = lane * 4;

    int start = (n == 0) ? 0 : pos[n - 1];
    int end = pos[n];

    float4 acc = make_float4(0.f, 0.f, 0.f, 0.f);
    for (int e = start; e < end; ++e) {
        int cl = ecol[e];
        float v = eval[e];
        float4 y = *(const float4*)(Y + (size_t)cl * N_CH + c);
        acc.x += v * y.x;
        acc.y += v * y.y;
        acc.z += v * y.z;
        acc.w += v * y.w;
    }

    float d = rsqrtf(deg[n] + 1.0f);
    float4 b = ((const float4*)bias)[lane];
    float4 o;
    o.x = acc.x * d + b.x;
    o.y = acc.y * d + b.y;
    o.z = acc.z * d + b.z;
    o.w = acc.w * d + b.w;
    ((float4*)(out + (size_t)n * N_CH))[lane] = o;
}

extern "C" void kernel_launch(void* const* d_in, const int* in_sizes, int n_in,
                              void* d_out, int out_size, void* d_ws, size_t ws_size,
                              hipStream_t stream) {
    const int*   row  = (const int*)d_in[0];
    const int*   col  = (const int*)d_in[1];
    const float* vals = (const float*)d_in[2];
    const float* X    = (const float*)d_in[3];
    const float* W    = (const float*)d_in[4];
    const float* bias = (const float*)d_in[5];
    float* out = (float*)d_out;

    const int E = in_sizes[0];
    const int N = in_sizes[3] / N_CH;
    const int nb = (N + 255) / 256;

    // workspace layout
    float* Y    = (float*)d_ws;                  // N*128 f32
    float* deg  = Y + (size_t)N * N_CH;          // N f32
    int*   cnt  = (int*)(deg + N);               // N i32
    int*   pos  = cnt + N;                       // N i32
    int*   ecol = pos + N;                       // E i32
    float* eval = (float*)(ecol + E);            // E f32
    int*   bsum = (int*)(eval + E);              // nb i32

    hipMemsetAsync(deg, 0, (size_t)N * sizeof(float), stream);
    hipMemsetAsync(cnt, 0, (size_t)N * sizeof(int), stream);

    degcnt_kernel<<<(E + 255) / 256, 256, 0, stream>>>(row, vals, deg, cnt, E);
    scan1_kernel<<<nb, 256, 0, stream>>>(cnt, pos, bsum, N);
    scan2_kernel<<<1, 512, 0, stream>>>(bsum, nb);
    scan3_kernel<<<nb, 256, 0, stream>>>(pos, bsum, N);
    csr_kernel<<<(E + 255) / 256, 256, 0, stream>>>(row, col, vals, pos, ecol, eval, E);

    gemm_kernel<<<(N + 31) / 32, 256, 0, stream>>>(X, W, deg, Y, N);

    unsigned gth = (unsigned)N * 32u;
    gather_kernel<<<(gth + 255) / 256, 256, 0, stream>>>(pos, ecol, eval, Y, deg, bias, out, N);
}

// Round 3
// 301.031 us; speedup vs baseline: 4.2689x; 1.0529x over previous
//
#include <hip/hip_runtime.h>
#include <hip/hip_bf16.h>

// GCNConv: out = D * (A @ (D * (X@W))) + bias,  D = rsqrt(rowsum(A)+1)
// N=100000, E=640000, C=128.
// R2: CSR gather replaced atomic scatter (1285->317us).
// R3: fp32 vector GEMM (66us, VALUBusy 52%, occ 17%) -> bf16 MFMA 16x16x32,
//     LDS-free, W pre-transposed to bf16, X converted in-register. Fused D-scale.

#define N_CH 128

typedef __attribute__((ext_vector_type(8))) short short8;
typedef __attribute__((ext_vector_type(4))) float f32x4;

__device__ inline unsigned short f2bf(float f) {
    unsigned u = __float_as_uint(f);
    return (unsigned short)((u + 0x7FFFu + ((u >> 16) & 1u)) >> 16);  // RNE
}

// ---- deg[r] += vals[e]; cnt[r] += 1 --------------------------------------
__global__ __launch_bounds__(256) void degcnt_kernel(const int* __restrict__ row,
                                                     const float* __restrict__ vals,
                                                     float* __restrict__ deg,
                                                     int* __restrict__ cnt, int E) {
    int e = blockIdx.x * 256 + threadIdx.x;
    if (e < E) {
        int r = row[e];
        atomicAdd(&deg[r], vals[e]);
        atomicAdd(&cnt[r], 1);
    }
}

// ---- exclusive scan of cnt -> pos (2-level) ------------------------------
__global__ __launch_bounds__(256) void scan1_kernel(const int* __restrict__ cnt,
                                                    int* __restrict__ pos,
                                                    int* __restrict__ bsum, int N) {
    __shared__ int s[256];
    int t = threadIdx.x;
    int i = blockIdx.x * 256 + t;
    int v = (i < N) ? cnt[i] : 0;
    s[t] = v;
    __syncthreads();
    for (int off = 1; off < 256; off <<= 1) {
        int x = (t >= off) ? s[t - off] : 0;
        __syncthreads();
        s[t] += x;
        __syncthreads();
    }
    if (i < N) pos[i] = s[t] - v;
    if (t == 255) bsum[blockIdx.x] = s[t];
}

__global__ __launch_bounds__(512) void scan2_kernel(int* __restrict__ bsum, int nb) {
    __shared__ int s[512];
    int t = threadIdx.x;
    int v = (t < nb) ? bsum[t] : 0;
    s[t] = v;
    __syncthreads();
    for (int off = 1; off < 512; off <<= 1) {
        int x = (t >= off) ? s[t - off] : 0;
        __syncthreads();
        s[t] += x;
        __syncthreads();
    }
    if (t < nb) bsum[t] = s[t] - v;
}

__global__ __launch_bounds__(256) void scan3_kernel(int* __restrict__ pos,
                                                    const int* __restrict__ bsum, int N) {
    int i = blockIdx.x * 256 + threadIdx.x;
    if (i < N) pos[i] += bsum[blockIdx.x];
}

// ---- CSR build -----------------------------------------------------------
__global__ __launch_bounds__(256) void csr_kernel(const int* __restrict__ row,
                                                  const int* __restrict__ col,
                                                  const float* __restrict__ vals,
                                                  int* __restrict__ pos,
                                                  int* __restrict__ ecol,
                                                  float* __restrict__ eval, int E) {
    int e = blockIdx.x * 256 + threadIdx.x;
    if (e < E) {
        int r = row[e];
        int p = atomicAdd(&pos[r], 1);
        ecol[p] = col[e];
        eval[p] = vals[e];
    }
}

// ---- W convert+transpose: Wt[n][k] = bf16(W[k][n]) -----------------------
__global__ __launch_bounds__(256) void wcvt_kernel(const float* __restrict__ W,
                                                   unsigned short* __restrict__ Wt) {
    int i = blockIdx.x * 256 + threadIdx.x;  // 16384 total
    int k = i >> 7, n = i & 127;
    Wt[n * N_CH + k] = f2bf(W[k * N_CH + n]);
}

// ---- Y[n,:] = rsqrt(deg[n]+1) * (X[n,:] @ W), bf16 MFMA ------------------
// One wave per 16-row x 128-col tile. No LDS. A from X fp32 (converted in reg),
// B from Wt bf16 (L1-resident 32KB). mfma_f32_16x16x32_bf16:
//   A[m][k]: m=lane&15, k=(lane>>4)*8+j ; B[k][n]: n=lane&15, same k
//   C/D: col=lane&15, row=(lane>>4)*4+reg
__global__ __launch_bounds__(256) void gemm_kernel(const float* __restrict__ X,
                                                   const unsigned short* __restrict__ Wt,
                                                   const float* __restrict__ deg,
                                                   float* __restrict__ Y, int N) {
    const int lane = threadIdx.x & 63;
    const int wv = threadIdx.x >> 6;
    const int base = (blockIdx.x * 4 + wv) * 16;
    if (base >= N) return;

    const int m = lane & 15;
    const int q = lane >> 4;

    // A fragments: 4 k-chunks, 8 fp32 each -> bf16
    short8 a[4];
    const float* xrow = X + (size_t)(base + m) * N_CH + q * 8;
#pragma unroll
    for (int c = 0; c < 4; ++c) {
        f32x4 lo = *(const f32x4*)(xrow + c * 32);
        f32x4 hi = *(const f32x4*)(xrow + c * 32 + 4);
        short8 v;
        v[0] = (short)f2bf(lo[0]); v[1] = (short)f2bf(lo[1]);
        v[2] = (short)f2bf(lo[2]); v[3] = (short)f2bf(lo[3]);
        v[4] = (short)f2bf(hi[0]); v[5] = (short)f2bf(hi[1]);
        v[6] = (short)f2bf(hi[2]); v[7] = (short)f2bf(hi[3]);
        a[c] = v;
    }

    f32x4 acc[8];
#pragma unroll
    for (int t = 0; t < 8; ++t) acc[t] = (f32x4){0.f, 0.f, 0.f, 0.f};

#pragma unroll
    for (int t = 0; t < 8; ++t) {
        const unsigned short* wrow = Wt + (size_t)(t * 16 + m) * N_CH + q * 8;
#pragma unroll
        for (int c = 0; c < 4; ++c) {
            short8 b = *(const short8*)(wrow + c * 32);
            acc[t] = __builtin_amdgcn_mfma_f32_16x16x32_bf16(a[c], b, acc[t], 0, 0, 0);
        }
    }

    // epilogue: D-scale + store (row = base + q*4 + reg, col = t*16 + m)
    float ds[4];
#pragma unroll
    for (int r = 0; r < 4; ++r) ds[r] = rsqrtf(deg[base + q * 4 + r] + 1.0f);

#pragma unroll
    for (int t = 0; t < 8; ++t) {
#pragma unroll
        for (int r = 0; r < 4; ++r) {
            Y[(size_t)(base + q * 4 + r) * N_CH + t * 16 + m] = acc[t][r] * ds[r];
        }
    }
}

// ---- gather: out[n,:] = D[n] * sum_e val_e * Y[col_e,:] + bias -----------
__global__ __launch_bounds__(256) void gather_kernel(const int* __restrict__ pos,
                                                     const int* __restrict__ ecol,
                                                     const float* __restrict__ eval,
                                                     const float* __restrict__ Y,
                                                     const float* __restrict__ deg,
                                                     const float* __restrict__ bias,
                                                     float* __restrict__ out, int N) {
    unsigned gid = blockIdx.x * 256u + threadIdx.x;
    int n = gid >> 5;
    if (n >= N) return;
    int lane = gid & 31;
    int c = lane * 4;

    int start = (n == 0) ? 0 : pos[n - 1];
    int end = pos[n];

    float4 acc = make_float4(0.f, 0.f, 0.f, 0.f);
    for (int e = start; e < end; ++e) {
        int cl = ecol[e];
        float v = eval[e];
        float4 y = *(const float4*)(Y + (size_t)cl * N_CH + c);
        acc.x += v * y.x;
        acc.y += v * y.y;
        acc.z += v * y.z;
        acc.w += v * y.w;
    }

    float d = rsqrtf(deg[n] + 1.0f);
    float4 b = ((const float4*)bias)[lane];
    float4 o;
    o.x = acc.x * d + b.x;
    o.y = acc.y * d + b.y;
    o.z = acc.z * d + b.z;
    o.w = acc.w * d + b.w;
    ((float4*)(out + (size_t)n * N_CH))[lane] = o;
}

extern "C" void kernel_launch(void* const* d_in, const int* in_sizes, int n_in,
                              void* d_out, int out_size, void* d_ws, size_t ws_size,
                              hipStream_t stream) {
    const int*   row  = (const int*)d_in[0];
    const int*   col  = (const int*)d_in[1];
    const float* vals = (const float*)d_in[2];
    const float* X    = (const float*)d_in[3];
    const float* W    = (const float*)d_in[4];
    const float* bias = (const float*)d_in[5];
    float* out = (float*)d_out;

    const int E = in_sizes[0];
    const int N = in_sizes[3] / N_CH;
    const int nb = (N + 255) / 256;

    // workspace layout
    float*          Y    = (float*)d_ws;                 // N*128 f32
    float*          deg  = Y + (size_t)N * N_CH;         // N f32
    int*            cnt  = (int*)(deg + N);              // N i32
    int*            pos  = cnt + N;                      // N i32
    int*            ecol = pos + N;                      // E i32
    float*          eval = (float*)(ecol + E);           // E f32
    int*            bsum = (int*)(eval + E);             // nb i32
    unsigned short* Wt   = (unsigned short*)(bsum + nb); // 128*128 bf16

    hipMemsetAsync(deg, 0, (size_t)N * sizeof(float), stream);
    hipMemsetAsync(cnt, 0, (size_t)N * sizeof(int), stream);

    degcnt_kernel<<<(E + 255) / 256, 256, 0, stream>>>(row, vals, deg, cnt, E);
    scan1_kernel<<<nb, 256, 0, stream>>>(cnt, pos, bsum, N);
    scan2_kernel<<<1, 512, 0, stream>>>(bsum, nb);
    scan3_kernel<<<nb, 256, 0, stream>>>(pos, bsum, N);
    csr_kernel<<<(E + 255) / 256, 256, 0, stream>>>(row, col, vals, pos, ecol, eval, E);

    wcvt_kernel<<<64, 256, 0, stream>>>(W, Wt);
    int tiles = (N + 15) / 16;                 // 6250 waves
    gemm_kernel<<<(tiles + 3) / 4, 256, 0, stream>>>(X, Wt, deg, Y, N);

    unsigned gth = (unsigned)N * 32u;
    gather_kernel<<<(gth + 255) / 256, 256, 0, stream>>>(pos, ecol, eval, Y, deg, bias, out, N);
}

// Round 4
// 242.021 us; speedup vs baseline: 5.3098x; 1.2438x over previous
//
#include <hip/hip_runtime.h>
#include <hip/hip_bf16.h>

// GCNConv: out = D * (A @ (D * (X@W))) + bias,  D = rsqrt(rowsum(A)+1)
// N=100000, E=640000, C=128.
// R2: CSR gather replaced atomic scatter (1285->317us).
// R3: bf16 MFMA GEMM (317->301us).
// R4: 1 atomic/edge (rank w/ return; CSR place + deg segment-sum atomic-free),
//     packed (col,val) uint2, bf16 Y (halves gather fetch + gemm write).

#define N_CH 128

typedef __attribute__((ext_vector_type(8))) short short8;
typedef __attribute__((ext_vector_type(4))) float f32x4;
typedef __attribute__((ext_vector_type(4))) unsigned short ushort4v;

__device__ inline unsigned short f2bf(float f) {
    unsigned u = __float_as_uint(f);
    return (unsigned short)((u + 0x7FFFu + ((u >> 16) & 1u)) >> 16);  // RNE
}
__device__ inline float bf2f(unsigned short h) {
    return __uint_as_float(((unsigned)h) << 16);
}

// ---- rank[e] = atomicAdd(&cnt[row[e]], 1) --------------------------------
__global__ __launch_bounds__(256) void rank_kernel(const int* __restrict__ row,
                                                   int* __restrict__ cnt,
                                                   int* __restrict__ rank, int E) {
    int e = blockIdx.x * 256 + threadIdx.x;
    if (e < E) rank[e] = atomicAdd(&cnt[row[e]], 1);
}

// ---- exclusive scan of cnt -> pos (2-level) ------------------------------
__global__ __launch_bounds__(256) void scan1_kernel(const int* __restrict__ cnt,
                                                    int* __restrict__ pos,
                                                    int* __restrict__ bsum, int N) {
    __shared__ int s[256];
    int t = threadIdx.x;
    int i = blockIdx.x * 256 + t;
    int v = (i < N) ? cnt[i] : 0;
    s[t] = v;
    __syncthreads();
    for (int off = 1; off < 256; off <<= 1) {
        int x = (t >= off) ? s[t - off] : 0;
        __syncthreads();
        s[t] += x;
        __syncthreads();
    }
    if (i < N) pos[i] = s[t] - v;
    if (t == 255) bsum[blockIdx.x] = s[t];
}

__global__ __launch_bounds__(512) void scan2_kernel(int* __restrict__ bsum, int nb) {
    __shared__ int s[512];
    int t = threadIdx.x;
    int v = (t < nb) ? bsum[t] : 0;
    s[t] = v;
    __syncthreads();
    for (int off = 1; off < 512; off <<= 1) {
        int x = (t >= off) ? s[t - off] : 0;
        __syncthreads();
        s[t] += x;
        __syncthreads();
    }
    if (t < nb) bsum[t] = s[t] - v;
}

__global__ __launch_bounds__(256) void scan3_kernel(int* __restrict__ pos,
                                                    const int* __restrict__ bsum, int N) {
    int i = blockIdx.x * 256 + threadIdx.x;
    if (i < N) pos[i] += bsum[blockIdx.x];
}

// ---- CSR place (no atomics): epack[pos[r]+rank[e]] = {col, val} ----------
__global__ __launch_bounds__(256) void place_kernel(const int* __restrict__ row,
                                                    const int* __restrict__ col,
                                                    const float* __restrict__ vals,
                                                    const int* __restrict__ pos,
                                                    const int* __restrict__ rank,
                                                    uint2* __restrict__ epack, int E) {
    int e = blockIdx.x * 256 + threadIdx.x;
    if (e < E) {
        int r = row[e];
        int p = pos[r] + rank[e];
        epack[p] = make_uint2((unsigned)col[e], __float_as_uint(vals[e]));
    }
}

// ---- dinv[n] = rsqrt(1 + sum of vals in row n) (segment sum, no atomics) -
__global__ __launch_bounds__(256) void dinv_kernel(const int* __restrict__ pos,
                                                   const uint2* __restrict__ epack,
                                                   float* __restrict__ dinv, int N, int E) {
    int n = blockIdx.x * 256 + threadIdx.x;
    if (n >= N) return;
    int start = pos[n];
    int end = (n + 1 < N) ? pos[n + 1] : E;
    float s = 0.f;
    for (int e = start; e < end; ++e) s += __uint_as_float(epack[e].y);
    dinv[n] = rsqrtf(s + 1.0f);
}

// ---- W convert+transpose: Wt[n][k] = bf16(W[k][n]) -----------------------
__global__ __launch_bounds__(256) void wcvt_kernel(const float* __restrict__ W,
                                                   unsigned short* __restrict__ Wt) {
    int i = blockIdx.x * 256 + threadIdx.x;  // 16384 total
    int k = i >> 7, n = i & 127;
    Wt[n * N_CH + k] = f2bf(W[k * N_CH + n]);
}

// ---- Ybf[n,:] = bf16( dinv[n] * (X[n,:] @ W) ), bf16 MFMA ----------------
// One wave per 16-row x 128-col tile. No LDS. A from X fp32 -> bf16 in reg,
// B from Wt (32KB, L1-resident). C/D: col=lane&15, row=(lane>>4)*4+reg.
__global__ __launch_bounds__(256) void gemm_kernel(const float* __restrict__ X,
                                                   const unsigned short* __restrict__ Wt,
                                                   const float* __restrict__ dinv,
                                                   unsigned short* __restrict__ Ybf, int N) {
    const int lane = threadIdx.x & 63;
    const int wv = threadIdx.x >> 6;
    const int base = (blockIdx.x * 4 + wv) * 16;
    if (base >= N) return;

    const int m = lane & 15;
    const int q = lane >> 4;

    short8 a[4];
    const float* xrow = X + (size_t)(base + m) * N_CH + q * 8;
#pragma unroll
    for (int c = 0; c < 4; ++c) {
        f32x4 lo = *(const f32x4*)(xrow + c * 32);
        f32x4 hi = *(const f32x4*)(xrow + c * 32 + 4);
        short8 v;
        v[0] = (short)f2bf(lo[0]); v[1] = (short)f2bf(lo[1]);
        v[2] = (short)f2bf(lo[2]); v[3] = (short)f2bf(lo[3]);
        v[4] = (short)f2bf(hi[0]); v[5] = (short)f2bf(hi[1]);
        v[6] = (short)f2bf(hi[2]); v[7] = (short)f2bf(hi[3]);
        a[c] = v;
    }

    f32x4 acc[8];
#pragma unroll
    for (int t = 0; t < 8; ++t) acc[t] = (f32x4){0.f, 0.f, 0.f, 0.f};

#pragma unroll
    for (int t = 0; t < 8; ++t) {
        const unsigned short* wrow = Wt + (size_t)(t * 16 + m) * N_CH + q * 8;
#pragma unroll
        for (int c = 0; c < 4; ++c) {
            short8 b = *(const short8*)(wrow + c * 32);
            acc[t] = __builtin_amdgcn_mfma_f32_16x16x32_bf16(a[c], b, acc[t], 0, 0, 0);
        }
    }

    float ds[4];
#pragma unroll
    for (int r = 0; r < 4; ++r) ds[r] = dinv[base + q * 4 + r];

#pragma unroll
    for (int t = 0; t < 8; ++t) {
#pragma unroll
        for (int r = 0; r < 4; ++r) {
            Ybf[(size_t)(base + q * 4 + r) * N_CH + t * 16 + m] = f2bf(acc[t][r] * ds[r]);
        }
    }
}

// ---- gather: out[n,:] = dinv[n] * sum_e val_e * Y[col_e,:] + bias --------
// 32 threads (half-wave) per node, bf16x4 per lane, register accumulate.
__global__ __launch_bounds__(256) void gather_kernel(const int* __restrict__ pos,
                                                     const uint2* __restrict__ epack,
                                                     const unsigned short* __restrict__ Ybf,
                                                     const float* __restrict__ dinv,
                                                     const float* __restrict__ bias,
                                                     float* __restrict__ out, int N, int E) {
    unsigned gid = blockIdx.x * 256u + threadIdx.x;
    int n = gid >> 5;
    if (n >= N) return;
    int lane = gid & 31;
    int c = lane * 4;

    int start = pos[n];
    int end = (n + 1 < N) ? pos[n + 1] : E;

    float4 acc = make_float4(0.f, 0.f, 0.f, 0.f);
    for (int e = start; e < end; ++e) {
        uint2 p = epack[e];            // broadcast across half-wave
        int cl = (int)p.x;
        float v = __uint_as_float(p.y);
        ushort4v y = *(const ushort4v*)(Ybf + (size_t)cl * N_CH + c);
        acc.x += v * bf2f(y[0]);
        acc.y += v * bf2f(y[1]);
        acc.z += v * bf2f(y[2]);
        acc.w += v * bf2f(y[3]);
    }

    float d = dinv[n];
    float4 b = ((const float4*)bias)[lane];
    float4 o;
    o.x = acc.x * d + b.x;
    o.y = acc.y * d + b.y;
    o.z = acc.z * d + b.z;
    o.w = acc.w * d + b.w;
    ((float4*)(out + (size_t)n * N_CH))[lane] = o;
}

extern "C" void kernel_launch(void* const* d_in, const int* in_sizes, int n_in,
                              void* d_out, int out_size, void* d_ws, size_t ws_size,
                              hipStream_t stream) {
    const int*   row  = (const int*)d_in[0];
    const int*   col  = (const int*)d_in[1];
    const float* vals = (const float*)d_in[2];
    const float* X    = (const float*)d_in[3];
    const float* W    = (const float*)d_in[4];
    const float* bias = (const float*)d_in[5];
    float* out = (float*)d_out;

    const int E = in_sizes[0];
    const int N = in_sizes[3] / N_CH;
    const int nb = (N + 255) / 256;
    const int eb = (E + 255) / 256;

    // workspace layout (8-byte aligned first)
    uint2*          epack = (uint2*)d_ws;                       // E uint2
    unsigned short* Ybf   = (unsigned short*)(epack + E);       // N*128 bf16
    float*          dinv  = (float*)(Ybf + (size_t)N * N_CH);   // N f32
    int*            cnt   = (int*)(dinv + N);                   // N i32
    int*            pos   = cnt + N;                            // N i32
    int*            rank  = pos + N;                            // E i32
    int*            bsum  = rank + E;                           // nb i32
    unsigned short* Wt    = (unsigned short*)(bsum + nb);       // 128*128 bf16

    hipMemsetAsync(cnt, 0, (size_t)N * sizeof(int), stream);

    rank_kernel<<<eb, 256, 0, stream>>>(row, cnt, rank, E);
    scan1_kernel<<<nb, 256, 0, stream>>>(cnt, pos, bsum, N);
    scan2_kernel<<<1, 512, 0, stream>>>(bsum, nb);
    scan3_kernel<<<nb, 256, 0, stream>>>(pos, bsum, N);
    place_kernel<<<eb, 256, 0, stream>>>(row, col, vals, pos, rank, epack, E);
    dinv_kernel<<<nb, 256, 0, stream>>>(pos, epack, dinv, N, E);

    wcvt_kernel<<<64, 256, 0, stream>>>(W, Wt);
    int tiles = (N + 15) / 16;
    gemm_kernel<<<(tiles + 3) / 4, 256, 0, stream>>>(X, Wt, dinv, Ybf, N);

    unsigned gth = (unsigned)N * 32u;
    gather_kernel<<<(gth + 255) / 256, 256, 0, stream>>>(pos, epack, Ybf, dinv, bias, out, N, E);
}

// Round 5
// 230.034 us; speedup vs baseline: 5.5865x; 1.0521x over previous
//
#include <hip/hip_runtime.h>
#include <hip/hip_bf16.h>

// GCNConv: out = D * (A @ (D * (X@W))) + bias,  D = rsqrt(rowsum(A)+1)
// N=100000, E=640000, C=128.
// R2: CSR gather replaced atomic scatter (1285->317us).
// R3: bf16 MFMA GEMM (317->301us).
// R4: 1 atomic/edge CSR build, packed uint2 edges, bf16 Y (301->242us).
// R5: memory-level parallelism: 8 atomics/thread in rank, 4 edges/thread in
//     place, 4-wide unrolled gather loop. All were 1-outstanding-op latency
//     bound (rank VALUBusy 0.26%, gather 2.5TB/s at 18% VALU).

#define N_CH 128

typedef __attribute__((ext_vector_type(8))) short short8;
typedef __attribute__((ext_vector_type(4))) float f32x4;
typedef __attribute__((ext_vector_type(4))) unsigned short ushort4v;

__device__ inline unsigned short f2bf(float f) {
    unsigned u = __float_as_uint(f);
    return (unsigned short)((u + 0x7FFFu + ((u >> 16) & 1u)) >> 16);  // RNE
}
__device__ inline float bf2f(unsigned short h) {
    return __uint_as_float(((unsigned)h) << 16);
}

// ---- rank[e] = atomicAdd(&cnt[row[e]], 1); 8 edges/thread ----------------
__global__ __launch_bounds__(256) void rank_kernel(const int* __restrict__ row,
                                                   int* __restrict__ cnt,
                                                   int* __restrict__ rank, int E) {
    int e0 = blockIdx.x * 2048 + threadIdx.x;
#pragma unroll
    for (int j = 0; j < 8; ++j) {
        int e = e0 + j * 256;
        if (e < E) rank[e] = atomicAdd(&cnt[row[e]], 1);
    }
}

// ---- exclusive scan of cnt -> pos (2-level) ------------------------------
__global__ __launch_bounds__(256) void scan1_kernel(const int* __restrict__ cnt,
                                                    int* __restrict__ pos,
                                                    int* __restrict__ bsum, int N) {
    __shared__ int s[256];
    int t = threadIdx.x;
    int i = blockIdx.x * 256 + t;
    int v = (i < N) ? cnt[i] : 0;
    s[t] = v;
    __syncthreads();
    for (int off = 1; off < 256; off <<= 1) {
        int x = (t >= off) ? s[t - off] : 0;
        __syncthreads();
        s[t] += x;
        __syncthreads();
    }
    if (i < N) pos[i] = s[t] - v;
    if (t == 255) bsum[blockIdx.x] = s[t];
}

__global__ __launch_bounds__(512) void scan2_kernel(int* __restrict__ bsum, int nb) {
    __shared__ int s[512];
    int t = threadIdx.x;
    int v = (t < nb) ? bsum[t] : 0;
    s[t] = v;
    __syncthreads();
    for (int off = 1; off < 512; off <<= 1) {
        int x = (t >= off) ? s[t - off] : 0;
        __syncthreads();
        s[t] += x;
        __syncthreads();
    }
    if (t < nb) bsum[t] = s[t] - v;
}

__global__ __launch_bounds__(256) void scan3_kernel(int* __restrict__ pos,
                                                    const int* __restrict__ bsum, int N) {
    int i = blockIdx.x * 256 + threadIdx.x;
    if (i < N) pos[i] += bsum[blockIdx.x];
}

// ---- CSR place (no atomics): epack[pos[r]+rank[e]] = {col,val}; 4/thread -
__global__ __launch_bounds__(256) void place_kernel(const int* __restrict__ row,
                                                    const int* __restrict__ col,
                                                    const float* __restrict__ vals,
                                                    const int* __restrict__ pos,
                                                    const int* __restrict__ rank,
                                                    uint2* __restrict__ epack, int E) {
    int e0 = blockIdx.x * 1024 + threadIdx.x;
#pragma unroll
    for (int j = 0; j < 4; ++j) {
        int e = e0 + j * 256;
        if (e < E) {
            int r = row[e];
            int p = pos[r] + rank[e];
            epack[p] = make_uint2((unsigned)col[e], __float_as_uint(vals[e]));
        }
    }
}

// ---- dinv[n] = rsqrt(1 + sum of vals in row n) ---------------------------
__global__ __launch_bounds__(256) void dinv_kernel(const int* __restrict__ pos,
                                                   const uint2* __restrict__ epack,
                                                   float* __restrict__ dinv, int N, int E) {
    int n = blockIdx.x * 256 + threadIdx.x;
    if (n >= N) return;
    int start = pos[n];
    int end = (n + 1 < N) ? pos[n + 1] : E;
    float s = 0.f;
    for (int e = start; e < end; ++e) s += __uint_as_float(epack[e].y);
    dinv[n] = rsqrtf(s + 1.0f);
}

// ---- W convert+transpose: Wt[n][k] = bf16(W[k][n]) -----------------------
__global__ __launch_bounds__(256) void wcvt_kernel(const float* __restrict__ W,
                                                   unsigned short* __restrict__ Wt) {
    int i = blockIdx.x * 256 + threadIdx.x;  // 16384 total
    int k = i >> 7, n = i & 127;
    Wt[n * N_CH + k] = f2bf(W[k * N_CH + n]);
}

// ---- Ybf[n,:] = bf16( dinv[n] * (X[n,:] @ W) ), bf16 MFMA ----------------
__global__ __launch_bounds__(256) void gemm_kernel(const float* __restrict__ X,
                                                   const unsigned short* __restrict__ Wt,
                                                   const float* __restrict__ dinv,
                                                   unsigned short* __restrict__ Ybf, int N) {
    const int lane = threadIdx.x & 63;
    const int wv = threadIdx.x >> 6;
    const int base = (blockIdx.x * 4 + wv) * 16;
    if (base >= N) return;

    const int m = lane & 15;
    const int q = lane >> 4;

    short8 a[4];
    const float* xrow = X + (size_t)(base + m) * N_CH + q * 8;
#pragma unroll
    for (int c = 0; c < 4; ++c) {
        f32x4 lo = *(const f32x4*)(xrow + c * 32);
        f32x4 hi = *(const f32x4*)(xrow + c * 32 + 4);
        short8 v;
        v[0] = (short)f2bf(lo[0]); v[1] = (short)f2bf(lo[1]);
        v[2] = (short)f2bf(lo[2]); v[3] = (short)f2bf(lo[3]);
        v[4] = (short)f2bf(hi[0]); v[5] = (short)f2bf(hi[1]);
        v[6] = (short)f2bf(hi[2]); v[7] = (short)f2bf(hi[3]);
        a[c] = v;
    }

    f32x4 acc[8];
#pragma unroll
    for (int t = 0; t < 8; ++t) acc[t] = (f32x4){0.f, 0.f, 0.f, 0.f};

#pragma unroll
    for (int t = 0; t < 8; ++t) {
        const unsigned short* wrow = Wt + (size_t)(t * 16 + m) * N_CH + q * 8;
#pragma unroll
        for (int c = 0; c < 4; ++c) {
            short8 b = *(const short8*)(wrow + c * 32);
            acc[t] = __builtin_amdgcn_mfma_f32_16x16x32_bf16(a[c], b, acc[t], 0, 0, 0);
        }
    }

    float ds[4];
#pragma unroll
    for (int r = 0; r < 4; ++r) ds[r] = dinv[base + q * 4 + r];

#pragma unroll
    for (int t = 0; t < 8; ++t) {
#pragma unroll
        for (int r = 0; r < 4; ++r) {
            Ybf[(size_t)(base + q * 4 + r) * N_CH + t * 16 + m] = f2bf(acc[t][r] * ds[r]);
        }
    }
}

// ---- gather: out[n,:] = dinv[n] * sum_e val_e * Y[col_e,:] + bias --------
// Half-wave per node, 4-wide unrolled edge loop for MLP.
__global__ __launch_bounds__(256) void gather_kernel(const int* __restrict__ pos,
                                                     const uint2* __restrict__ epack,
                                                     const unsigned short* __restrict__ Ybf,
                                                     const float* __restrict__ dinv,
                                                     const float* __restrict__ bias,
                                                     float* __restrict__ out, int N, int E) {
    unsigned gid = blockIdx.x * 256u + threadIdx.x;
    int n = gid >> 5;
    if (n >= N) return;
    int lane = gid & 31;
    int c = lane * 4;

    int e = pos[n];
    int end = (n + 1 < N) ? pos[n + 1] : E;

    float4 acc = make_float4(0.f, 0.f, 0.f, 0.f);
    for (; e + 4 <= end; e += 4) {
        uint2 p0 = epack[e + 0];
        uint2 p1 = epack[e + 1];
        uint2 p2 = epack[e + 2];
        uint2 p3 = epack[e + 3];
        ushort4v y0 = *(const ushort4v*)(Ybf + (size_t)p0.x * N_CH + c);
        ushort4v y1 = *(const ushort4v*)(Ybf + (size_t)p1.x * N_CH + c);
        ushort4v y2 = *(const ushort4v*)(Ybf + (size_t)p2.x * N_CH + c);
        ushort4v y3 = *(const ushort4v*)(Ybf + (size_t)p3.x * N_CH + c);
        float v0 = __uint_as_float(p0.y);
        float v1 = __uint_as_float(p1.y);
        float v2 = __uint_as_float(p2.y);
        float v3 = __uint_as_float(p3.y);
        acc.x += v0 * bf2f(y0[0]) + v1 * bf2f(y1[0]) + v2 * bf2f(y2[0]) + v3 * bf2f(y3[0]);
        acc.y += v0 * bf2f(y0[1]) + v1 * bf2f(y1[1]) + v2 * bf2f(y2[1]) + v3 * bf2f(y3[1]);
        acc.z += v0 * bf2f(y0[2]) + v1 * bf2f(y1[2]) + v2 * bf2f(y2[2]) + v3 * bf2f(y3[2]);
        acc.w += v0 * bf2f(y0[3]) + v1 * bf2f(y1[3]) + v2 * bf2f(y2[3]) + v3 * bf2f(y3[3]);
    }
    for (; e < end; ++e) {
        uint2 p = epack[e];
        float v = __uint_as_float(p.y);
        ushort4v y = *(const ushort4v*)(Ybf + (size_t)p.x * N_CH + c);
        acc.x += v * bf2f(y[0]);
        acc.y += v * bf2f(y[1]);
        acc.z += v * bf2f(y[2]);
        acc.w += v * bf2f(y[3]);
    }

    float d = dinv[n];
    float4 b = ((const float4*)bias)[lane];
    float4 o;
    o.x = acc.x * d + b.x;
    o.y = acc.y * d + b.y;
    o.z = acc.z * d + b.z;
    o.w = acc.w * d + b.w;
    ((float4*)(out + (size_t)n * N_CH))[lane] = o;
}

extern "C" void kernel_launch(void* const* d_in, const int* in_sizes, int n_in,
                              void* d_out, int out_size, void* d_ws, size_t ws_size,
                              hipStream_t stream) {
    const int*   row  = (const int*)d_in[0];
    const int*   col  = (const int*)d_in[1];
    const float* vals = (const float*)d_in[2];
    const float* X    = (const float*)d_in[3];
    const float* W    = (const float*)d_in[4];
    const float* bias = (const float*)d_in[5];
    float* out = (float*)d_out;

    const int E = in_sizes[0];
    const int N = in_sizes[3] / N_CH;
    const int nb = (N + 255) / 256;

    // workspace layout (8-byte aligned first)
    uint2*          epack = (uint2*)d_ws;                       // E uint2
    unsigned short* Ybf   = (unsigned short*)(epack + E);       // N*128 bf16
    float*          dinv  = (float*)(Ybf + (size_t)N * N_CH);   // N f32
    int*            cnt   = (int*)(dinv + N);                   // N i32
    int*            pos   = cnt + N;                            // N i32
    int*            rank  = pos + N;                            // E i32
    int*            bsum  = rank + E;                           // nb i32
    unsigned short* Wt    = (unsigned short*)(bsum + nb);       // 128*128 bf16

    hipMemsetAsync(cnt, 0, (size_t)N * sizeof(int), stream);

    rank_kernel<<<(E + 2047) / 2048, 256, 0, stream>>>(row, cnt, rank, E);
    scan1_kernel<<<nb, 256, 0, stream>>>(cnt, pos, bsum, N);
    scan2_kernel<<<1, 512, 0, stream>>>(bsum, nb);
    scan3_kernel<<<nb, 256, 0, stream>>>(pos, bsum, N);
    place_kernel<<<(E + 1023) / 1024, 256, 0, stream>>>(row, col, vals, pos, rank, epack, E);
    dinv_kernel<<<nb, 256, 0, stream>>>(pos, epack, dinv, N, E);

    wcvt_kernel<<<64, 256, 0, stream>>>(W, Wt);
    int tiles = (N + 15) / 16;
    gemm_kernel<<<(tiles + 3) / 4, 256, 0, stream>>>(X, Wt, dinv, Ybf, N);

    unsigned gth = (unsigned)N * 32u;
    gather_kernel<<<(gth + 255) / 256, 256, 0, stream>>>(pos, epack, Ybf, dinv, bias, out, N, E);
}

// Round 6
// 216.315 us; speedup vs baseline: 5.9408x; 1.0634x over previous
//
#include <hip/hip_runtime.h>
#include <hip/hip_bf16.h>

// GCNConv: out = D * (A @ (D * (X@W))) + bias,  D = rsqrt(rowsum(A)+1)
// N=100000, E=640000, C=128.
// R2: CSR gather replaced atomic scatter (1285->317us).
// R3: bf16 MFMA GEMM (317->301us).
// R4: 1 atomic/edge CSR build, packed uint2 edges, bf16 Y (301->242us).
// R5: MLP unrolls in rank/place/gather (242->230us).
// R6: gemm was latency-bound on per-wave global Wt re-fetch (41us, MfmaUtil
//     2.7%, VALU 6%): stage Wt in LDS once/block (row stride 136 ushorts ->
//     2 lanes/bank, conflict-free), 2 row-tiles per wave.

#define N_CH 128
#define WT_LD 136  // padded LDS row stride (ushorts): banks (4m+4q)%32 -> 2-way max

typedef __attribute__((ext_vector_type(8))) short short8;
typedef __attribute__((ext_vector_type(4))) float f32x4;
typedef __attribute__((ext_vector_type(4))) unsigned short ushort4v;

__device__ inline unsigned short f2bf(float f) {
    unsigned u = __float_as_uint(f);
    return (unsigned short)((u + 0x7FFFu + ((u >> 16) & 1u)) >> 16);  // RNE
}
__device__ inline float bf2f(unsigned short h) {
    return __uint_as_float(((unsigned)h) << 16);
}

// ---- rank[e] = atomicAdd(&cnt[row[e]], 1); 8 edges/thread ----------------
__global__ __launch_bounds__(256) void rank_kernel(const int* __restrict__ row,
                                                   int* __restrict__ cnt,
                                                   int* __restrict__ rank, int E) {
    int e0 = blockIdx.x * 2048 + threadIdx.x;
#pragma unroll
    for (int j = 0; j < 8; ++j) {
        int e = e0 + j * 256;
        if (e < E) rank[e] = atomicAdd(&cnt[row[e]], 1);
    }
}

// ---- exclusive scan of cnt -> pos (2-level) ------------------------------
__global__ __launch_bounds__(256) void scan1_kernel(const int* __restrict__ cnt,
                                                    int* __restrict__ pos,
                                                    int* __restrict__ bsum, int N) {
    __shared__ int s[256];
    int t = threadIdx.x;
    int i = blockIdx.x * 256 + t;
    int v = (i < N) ? cnt[i] : 0;
    s[t] = v;
    __syncthreads();
    for (int off = 1; off < 256; off <<= 1) {
        int x = (t >= off) ? s[t - off] : 0;
        __syncthreads();
        s[t] += x;
        __syncthreads();
    }
    if (i < N) pos[i] = s[t] - v;
    if (t == 255) bsum[blockIdx.x] = s[t];
}

__global__ __launch_bounds__(512) void scan2_kernel(int* __restrict__ bsum, int nb) {
    __shared__ int s[512];
    int t = threadIdx.x;
    int v = (t < nb) ? bsum[t] : 0;
    s[t] = v;
    __syncthreads();
    for (int off = 1; off < 512; off <<= 1) {
        int x = (t >= off) ? s[t - off] : 0;
        __syncthreads();
        s[t] += x;
        __syncthreads();
    }
    if (t < nb) bsum[t] = s[t] - v;
}

__global__ __launch_bounds__(256) void scan3_kernel(int* __restrict__ pos,
                                                    const int* __restrict__ bsum, int N) {
    int i = blockIdx.x * 256 + threadIdx.x;
    if (i < N) pos[i] += bsum[blockIdx.x];
}

// ---- CSR place (no atomics): epack[pos[r]+rank[e]] = {col,val}; 4/thread -
__global__ __launch_bounds__(256) void place_kernel(const int* __restrict__ row,
                                                    const int* __restrict__ col,
                                                    const float* __restrict__ vals,
                                                    const int* __restrict__ pos,
                                                    const int* __restrict__ rank,
                                                    uint2* __restrict__ epack, int E) {
    int e0 = blockIdx.x * 1024 + threadIdx.x;
#pragma unroll
    for (int j = 0; j < 4; ++j) {
        int e = e0 + j * 256;
        if (e < E) {
            int r = row[e];
            int p = pos[r] + rank[e];
            epack[p] = make_uint2((unsigned)col[e], __float_as_uint(vals[e]));
        }
    }
}

// ---- dinv[n] = rsqrt(1 + sum of vals in row n) ---------------------------
__global__ __launch_bounds__(256) void dinv_kernel(const int* __restrict__ pos,
                                                   const uint2* __restrict__ epack,
                                                   float* __restrict__ dinv, int N, int E) {
    int n = blockIdx.x * 256 + threadIdx.x;
    if (n >= N) return;
    int start = pos[n];
    int end = (n + 1 < N) ? pos[n + 1] : E;
    float s = 0.f;
    for (int e = start; e < end; ++e) s += __uint_as_float(epack[e].y);
    dinv[n] = rsqrtf(s + 1.0f);
}

// ---- W convert+transpose: Wt[n][k] = bf16(W[k][n]) -----------------------
__global__ __launch_bounds__(256) void wcvt_kernel(const float* __restrict__ W,
                                                   unsigned short* __restrict__ Wt) {
    int i = blockIdx.x * 256 + threadIdx.x;  // 16384 total
    int k = i >> 7, n = i & 127;
    Wt[n * N_CH + k] = f2bf(W[k * N_CH + n]);
}

// ---- Ybf[n,:] = bf16( dinv[n] * (X[n,:] @ W) ), bf16 MFMA ----------------
// Block = 4 waves, 128 rows. Wt staged in LDS (padded stride -> no bank
// conflicts); each wave does 2 16-row tiles. A from X fp32 -> bf16 in reg.
// C/D: col=lane&15, row=(lane>>4)*4+reg.
__global__ __launch_bounds__(256) void gemm_kernel(const float* __restrict__ X,
                                                   const unsigned short* __restrict__ Wt,
                                                   const float* __restrict__ dinv,
                                                   unsigned short* __restrict__ Ybf, int N) {
    __shared__ unsigned short Wl[N_CH * WT_LD];  // 34 KB

    const int t = threadIdx.x;
    // stage Wt (16384 ushorts = 2048 short8 chunks, 8 per thread)
    const short8* Wg = (const short8*)Wt;
#pragma unroll
    for (int j = 0; j < 8; ++j) {
        int idx = t + 256 * j;          // chunk id
        int r = idx >> 4, cc = idx & 15;
        *(short8*)(Wl + r * WT_LD + cc * 8) = Wg[idx];
    }
    __syncthreads();

    const int lane = t & 63;
    const int wv = t >> 6;
    const int m = lane & 15;
    const int q = lane >> 4;

#pragma unroll
    for (int i = 0; i < 2; ++i) {
        const int base = (blockIdx.x * 8 + wv * 2 + i) * 16;
        if (base >= N) break;

        // A fragments: 4 k-chunks, 8 fp32 each -> bf16
        short8 a[4];
        const float* xrow = X + (size_t)(base + m) * N_CH + q * 8;
#pragma unroll
        for (int c = 0; c < 4; ++c) {
            f32x4 lo = *(const f32x4*)(xrow + c * 32);
            f32x4 hi = *(const f32x4*)(xrow + c * 32 + 4);
            short8 v;
            v[0] = (short)f2bf(lo[0]); v[1] = (short)f2bf(lo[1]);
            v[2] = (short)f2bf(lo[2]); v[3] = (short)f2bf(lo[3]);
            v[4] = (short)f2bf(hi[0]); v[5] = (short)f2bf(hi[1]);
            v[6] = (short)f2bf(hi[2]); v[7] = (short)f2bf(hi[3]);
            a[c] = v;
        }

        f32x4 acc[8];
#pragma unroll
        for (int tt = 0; tt < 8; ++tt) acc[tt] = (f32x4){0.f, 0.f, 0.f, 0.f};

#pragma unroll
        for (int tt = 0; tt < 8; ++tt) {
            const unsigned short* wrow = Wl + (tt * 16 + m) * WT_LD + q * 8;
#pragma unroll
            for (int c = 0; c < 4; ++c) {
                short8 b = *(const short8*)(wrow + c * 32);
                acc[tt] = __builtin_amdgcn_mfma_f32_16x16x32_bf16(a[c], b, acc[tt], 0, 0, 0);
            }
        }

        float ds[4];
#pragma unroll
        for (int r = 0; r < 4; ++r) ds[r] = dinv[base + q * 4 + r];

#pragma unroll
        for (int tt = 0; tt < 8; ++tt) {
#pragma unroll
            for (int r = 0; r < 4; ++r) {
                Ybf[(size_t)(base + q * 4 + r) * N_CH + tt * 16 + m] = f2bf(acc[tt][r] * ds[r]);
            }
        }
    }
}

// ---- gather: out[n,:] = dinv[n] * sum_e val_e * Y[col_e,:] + bias --------
__global__ __launch_bounds__(256) void gather_kernel(const int* __restrict__ pos,
                                                     const uint2* __restrict__ epack,
                                                     const unsigned short* __restrict__ Ybf,
                                                     const float* __restrict__ dinv,
                                                     const float* __restrict__ bias,
                                                     float* __restrict__ out, int N, int E) {
    unsigned gid = blockIdx.x * 256u + threadIdx.x;
    int n = gid >> 5;
    if (n >= N) return;
    int lane = gid & 31;
    int c = lane * 4;

    int e = pos[n];
    int end = (n + 1 < N) ? pos[n + 1] : E;

    float4 acc = make_float4(0.f, 0.f, 0.f, 0.f);
    for (; e + 4 <= end; e += 4) {
        uint2 p0 = epack[e + 0];
        uint2 p1 = epack[e + 1];
        uint2 p2 = epack[e + 2];
        uint2 p3 = epack[e + 3];
        ushort4v y0 = *(const ushort4v*)(Ybf + (size_t)p0.x * N_CH + c);
        ushort4v y1 = *(const ushort4v*)(Ybf + (size_t)p1.x * N_CH + c);
        ushort4v y2 = *(const ushort4v*)(Ybf + (size_t)p2.x * N_CH + c);
        ushort4v y3 = *(const ushort4v*)(Ybf + (size_t)p3.x * N_CH + c);
        float v0 = __uint_as_float(p0.y);
        float v1 = __uint_as_float(p1.y);
        float v2 = __uint_as_float(p2.y);
        float v3 = __uint_as_float(p3.y);
        acc.x += v0 * bf2f(y0[0]) + v1 * bf2f(y1[0]) + v2 * bf2f(y2[0]) + v3 * bf2f(y3[0]);
        acc.y += v0 * bf2f(y0[1]) + v1 * bf2f(y1[1]) + v2 * bf2f(y2[1]) + v3 * bf2f(y3[1]);
        acc.z += v0 * bf2f(y0[2]) + v1 * bf2f(y1[2]) + v2 * bf2f(y2[2]) + v3 * bf2f(y3[2]);
        acc.w += v0 * bf2f(y0[3]) + v1 * bf2f(y1[3]) + v2 * bf2f(y2[3]) + v3 * bf2f(y3[3]);
    }
    for (; e < end; ++e) {
        uint2 p = epack[e];
        float v = __uint_as_float(p.y);
        ushort4v y = *(const ushort4v*)(Ybf + (size_t)p.x * N_CH + c);
        acc.x += v * bf2f(y[0]);
        acc.y += v * bf2f(y[1]);
        acc.z += v * bf2f(y[2]);
        acc.w += v * bf2f(y[3]);
    }

    float d = dinv[n];
    float4 b = ((const float4*)bias)[lane];
    float4 o;
    o.x = acc.x * d + b.x;
    o.y = acc.y * d + b.y;
    o.z = acc.z * d + b.z;
    o.w = acc.w * d + b.w;
    ((float4*)(out + (size_t)n * N_CH))[lane] = o;
}

extern "C" void kernel_launch(void* const* d_in, const int* in_sizes, int n_in,
                              void* d_out, int out_size, void* d_ws, size_t ws_size,
                              hipStream_t stream) {
    const int*   row  = (const int*)d_in[0];
    const int*   col  = (const int*)d_in[1];
    const float* vals = (const float*)d_in[2];
    const float* X    = (const float*)d_in[3];
    const float* W    = (const float*)d_in[4];
    const float* bias = (const float*)d_in[5];
    float* out = (float*)d_out;

    const int E = in_sizes[0];
    const int N = in_sizes[3] / N_CH;
    const int nb = (N + 255) / 256;

    // workspace layout (8-byte aligned first)
    uint2*          epack = (uint2*)d_ws;                       // E uint2
    unsigned short* Ybf   = (unsigned short*)(epack + E);       // N*128 bf16
    float*          dinv  = (float*)(Ybf + (size_t)N * N_CH);   // N f32
    int*            cnt   = (int*)(dinv + N);                   // N i32
    int*            pos   = cnt + N;                            // N i32
    int*            rank  = pos + N;                            // E i32
    int*            bsum  = rank + E;                           // nb i32
    unsigned short* Wt    = (unsigned short*)(bsum + nb);       // 128*128 bf16

    hipMemsetAsync(cnt, 0, (size_t)N * sizeof(int), stream);

    rank_kernel<<<(E + 2047) / 2048, 256, 0, stream>>>(row, cnt, rank, E);
    scan1_kernel<<<nb, 256, 0, stream>>>(cnt, pos, bsum, N);
    scan2_kernel<<<1, 512, 0, stream>>>(bsum, nb);
    scan3_kernel<<<nb, 256, 0, stream>>>(pos, bsum, N);
    place_kernel<<<(E + 1023) / 1024, 256, 0, stream>>>(row, col, vals, pos, rank, epack, E);
    dinv_kernel<<<nb, 256, 0, stream>>>(pos, epack, dinv, N, E);

    wcvt_kernel<<<64, 256, 0, stream>>>(W, Wt);
    int tiles = (N + 15) / 16;               // 6250
    int gblocks = (tiles + 7) / 8;           // 8 tiles per block (4 waves x 2)
    gemm_kernel<<<gblocks, 256, 0, stream>>>(X, Wt, dinv, Ybf, N);

    unsigned gth = (unsigned)N * 32u;
    gather_kernel<<<(gth + 255) / 256, 256, 0, stream>>>(pos, epack, Ybf, dinv, bias, out, N, E);
}